// Round 1
// 287.011 us; speedup vs baseline: 1.0743x; 1.0743x over previous
//
#include <hip/hip_runtime.h>

#define HW 3136
#define NPOS 12845056   // 16*256*3136

__device__ __forceinline__ unsigned fkey(float f) {
  unsigned u = __float_as_uint(f);
  return (u & 0x80000000u) ? ~u : (u | 0x80000000u);
}
__device__ __forceinline__ float funkey(unsigned u) {
  return __uint_as_float((u & 0x80000000u) ? (u & 0x7FFFFFFFu) : ~u);
}
__device__ __forceinline__ float spikef(float x) {
  return fminf(fmaxf(rintf(x), 0.0f), 4.0f);
}

// ---------------- Kernel 1: transposes + audio pre-projection + init ----------------
__global__ __launch_bounds__(256) void prep_kernel(
    const float* __restrict__ audio, const float* __restrict__ w1,
    const float* __restrict__ b1, const float* __restrict__ w2,
    float* __restrict__ a_pre, float* __restrict__ w1t,
    float* __restrict__ w2t, float* __restrict__ pool,
    unsigned* __restrict__ mm)
{
  __shared__ float au[256];
  const int bx = blockIdx.x, t = threadIdx.x;
  if (bx < 128) {                       // w1 visual half -> w1t[c][j]
    int idx = bx * 256 + t;             // 32768
    int c = idx >> 7, j = idx & 127;
    w1t[idx] = w1[j * 512 + c];
  } else if (bx < 160) {                // w2 -> w2t[k][j2]
    int idx = (bx - 128) * 256 + t;     // 8192
    int k = idx >> 6, j2 = idx & 63;
    w2t[idx] = w2[j2 * 128 + k];
  } else if (bx < 176) {                // a_pre[b][j] = b1[j] + w1[j][256:512].audio[b]
    int b = bx - 160;
    au[t] = audio[b * 256 + t];
    __syncthreads();
    int w = t >> 6, l = t & 63;
    float a0 = au[l], a1 = au[l + 64], a2 = au[l + 128], a3 = au[l + 192];
    for (int jj = 0; jj < 32; ++jj) {
      int j = w * 32 + jj;
      const float* row = w1 + j * 512 + 256;
      float s = row[l] * a0 + row[l + 64] * a1 + row[l + 128] * a2 + row[l + 192] * a3;
      #pragma unroll
      for (int off = 32; off; off >>= 1) s += __shfl_xor(s, off);
      if (l == 0) a_pre[b * 128 + j] = s + b1[j];
    }
  } else {
    for (int i = t; i < 4096; i += 256) pool[i] = 0.0f;
    if (t == 0) { mm[0] = 0xFFFFFFFFu; mm[1] = 0u; }
  }
}

// ---------------- Kernel 2: fused MLP + mi + pooling ----------------
// Round-7 restructure: lane = position (64 pos/wave), each wave owns a 32-wide
// j-slice in registers (acc[32]). GEMM1/GEMM2 B-operand is wave-uniform ->
// scalar (SMEM) loads; fm is one coalesced global_load_dword per k. NO LDS and
// NO barriers in the GEMM loops (old version: 3 ds_read_b128 / 32 FMAs = 2x
// LDS-pipe oversubscription + ~27 barriers -> 24% VALUBusy). LDS only for the
// h1 handoff [128 j][64 pos] (32 KB) and cross-wave LN partials (2 KB);
// 6 barriers total. 34 KB LDS, ~3 blocks/CU.
__global__ __launch_bounds__(256, 3) void mlp_kernel(
    const float* __restrict__ fm, const float* __restrict__ w1t,
    const float* __restrict__ w2t, const float* __restrict__ b2,
    const float* __restrict__ w3, const float* __restrict__ b3,
    const float* __restrict__ g1, const float* __restrict__ be1,
    const float* __restrict__ g2, const float* __restrict__ be2,
    const float* __restrict__ a_pre, float* __restrict__ mi_out,
    float* __restrict__ pool, unsigned* __restrict__ mm)
{
  __shared__ float h1f[128 * 64];   // 32 KB: spiked h1, [j][pos]
  __shared__ float red[8][64];      // 2 KB: cross-wave LN partials

  const int b  = blockIdx.y;
  const int s0 = blockIdx.x * 64;
  const int t  = threadIdx.x;
  const int l  = t & 63;                                   // lane = position
  const int wv = __builtin_amdgcn_readfirstlane(t >> 6);   // wave-uniform

  const float* fmblk = fm + (size_t)b * 256 * HW + s0;

  // ---- GEMM1: acc[j] = sum_k fm[k][pos] * w1t[k][wv*32+j], K=256 ----
  float acc[32];
  #pragma unroll
  for (int j = 0; j < 32; ++j) acc[j] = 0.f;
  {
    const float*  fp = fmblk + l;
    const float4* wr = (const float4*)(w1t + wv * 32);     // row k: +32 float4
    #pragma unroll 4
    for (int k = 0; k < 256; ++k) {
      float x = *fp; fp += HW;                             // coalesced 256B/wave
      #pragma unroll
      for (int q = 0; q < 8; ++q) {
        float4 w4 = wr[q];                                 // uniform -> s_load
        acc[4*q+0] = fmaf(x, w4.x, acc[4*q+0]);
        acc[4*q+1] = fmaf(x, w4.y, acc[4*q+1]);
        acc[4*q+2] = fmaf(x, w4.z, acc[4*q+2]);
        acc[4*q+3] = fmaf(x, w4.w, acc[4*q+3]);
      }
      wr += 32;
    }
  }
  {   // bias + audio pre-projection (uniform per j)
    const float4* ap = (const float4*)(a_pre + b * 128 + wv * 32);
    #pragma unroll
    for (int q = 0; q < 8; ++q) {
      float4 a4 = ap[q];
      acc[4*q+0] += a4.x; acc[4*q+1] += a4.y;
      acc[4*q+2] += a4.z; acc[4*q+3] += a4.w;
    }
  }

  // ---- LN1 over j=128 (32 in-thread + 4-way cross-wave) ----
  float mu, inv;
  {
    float s = 0.f;
    #pragma unroll
    for (int j = 0; j < 32; ++j) s += acc[j];
    red[wv][l] = s;
    __syncthreads();
    mu = (red[0][l] + red[1][l] + red[2][l] + red[3][l]) * (1.0f/128.0f);
    float s2 = 0.f;
    #pragma unroll
    for (int j = 0; j < 32; ++j) { float d = acc[j] - mu; s2 = fmaf(d, d, s2); }
    red[4 + wv][l] = s2;
    __syncthreads();
    float var = (red[4][l] + red[5][l] + red[6][l] + red[7][l]) * (1.0f/128.0f);
    inv = 1.0f / sqrtf(var + 1e-5f);
  }

  // ---- spike -> h1f[j][pos] ----
  {
    const float* gp = g1  + wv * 32;
    const float* bp = be1 + wv * 32;
    #pragma unroll
    for (int j = 0; j < 32; ++j) {
      float h = spikef((acc[j] - mu) * inv * gp[j] + bp[j]);
      h1f[(wv * 32 + j) * 64 + l] = h;                     // 2-way bank, free
    }
  }
  __syncthreads();                                         // h1f resident

  // ---- GEMM2: a2[j2] = sum_k h1[k][pos] * w2t[k][wv*16+j2], K=128 ----
  float a2[16];
  #pragma unroll
  for (int j = 0; j < 16; ++j) a2[j] = 0.f;
  {
    const float*  hp = h1f + l;
    const float4* wr = (const float4*)(w2t + wv * 16);     // row k: +16 float4
    #pragma unroll 4
    for (int k = 0; k < 128; ++k) {
      float h = *hp; hp += 64;                             // 2-way bank, free
      #pragma unroll
      for (int q = 0; q < 4; ++q) {
        float4 w4 = wr[q];                                 // uniform -> s_load
        a2[4*q+0] = fmaf(h, w4.x, a2[4*q+0]);
        a2[4*q+1] = fmaf(h, w4.y, a2[4*q+1]);
        a2[4*q+2] = fmaf(h, w4.z, a2[4*q+2]);
        a2[4*q+3] = fmaf(h, w4.w, a2[4*q+3]);
      }
      wr += 16;
    }
  }
  {   // + b2
    const float4* bp = (const float4*)(b2 + wv * 16);
    #pragma unroll
    for (int q = 0; q < 4; ++q) {
      float4 b4 = bp[q];
      a2[4*q+0] += b4.x; a2[4*q+1] += b4.y;
      a2[4*q+2] += b4.z; a2[4*q+3] += b4.w;
    }
  }

  // ---- LN2 over j2=64 (16 in-thread + 4-way cross-wave) ----
  float mu2, inv2;
  {
    float s = 0.f;
    #pragma unroll
    for (int j = 0; j < 16; ++j) s += a2[j];
    red[wv][l] = s;
    __syncthreads();
    mu2 = (red[0][l] + red[1][l] + red[2][l] + red[3][l]) * (1.0f/64.0f);
    float s2 = 0.f;
    #pragma unroll
    for (int j = 0; j < 16; ++j) { float d = a2[j] - mu2; s2 = fmaf(d, d, s2); }
    red[4 + wv][l] = s2;
    __syncthreads();
    float var = (red[4][l] + red[5][l] + red[6][l] + red[7][l]) * (1.0f/64.0f);
    inv2 = 1.0f / sqrtf(var + 1e-5f);
  }

  // ---- spike + mi = h2 . w3 + b3 ----
  {
    const float* gp = g2  + wv * 16;
    const float* bp = be2 + wv * 16;
    const float* wp = w3  + wv * 16;
    float p = 0.f;
    #pragma unroll
    for (int j = 0; j < 16; ++j) {
      float sp = spikef((a2[j] - mu2) * inv2 * gp[j] + bp[j]);
      p = fmaf(sp, wp[j], p);
    }
    red[wv][l] = p;
  }
  __syncthreads();
  const float mi = red[0][l] + red[1][l] + red[2][l] + red[3][l] + b3[0];

  if (wv == 0) {
    mi_out[b * HW + s0 + l] = mi;                          // coalesced 256B
    float mn = mi, mx = mi;
    #pragma unroll
    for (int off = 32; off; off >>= 1) {
      mn = fminf(mn, __shfl_xor(mn, off));
      mx = fmaxf(mx, __shfl_xor(mx, off));
    }
    if (l == 0) {
      unsigned kmn = fkey(mn), kmx = fkey(mx);
      volatile unsigned* vmm = (volatile unsigned*)mm;
      if (kmn < vmm[0]) atomicMin(&mm[0], kmn);
      if (kmx > vmm[1]) atomicMax(&mm[1], kmx);
    }
  }

  // ---- pooling: pool[b][c] += sum_pos mi[pos]*fm[b][c][pos] ----
  {
    const float* fp = fmblk + l + (size_t)(wv << 6) * HW;
    #pragma unroll 4
    for (int ci = 0; ci < 64; ++ci) {
      float v = *fp * mi; fp += HW;
      #pragma unroll
      for (int off = 32; off; off >>= 1) v += __shfl_xor(v, off);
      if (l == 0) atomicAdd(&pool[b * 256 + (wv << 6) + ci], v);
    }
  }
}

// ---------------- Kernel 3: projection + LN + spike -> channel scale ----------------
__global__ __launch_bounds__(256) void scale_kernel(
    const float* __restrict__ pool, const float* __restrict__ pw,
    const float* __restrict__ pb, const float* __restrict__ pg,
    const float* __restrict__ pbeta, float* __restrict__ scale,
    const unsigned* __restrict__ mm, float* __restrict__ gpar)
{
  __shared__ float pl[256];
  __shared__ float xsh[256];
  __shared__ float rs[4], rs2[4];
  int b = blockIdx.x, t = threadIdx.x;
  pl[t] = pool[b*256 + t];
  __syncthreads();
  int w = t >> 6, l = t & 63;
  float p0 = pl[l], p1 = pl[l+64], p2 = pl[l+128], p3 = pl[l+192];
  for (int jj = 0; jj < 64; ++jj) {
    int j = w*64 + jj;
    const float* row = pw + j*256;
    float s = row[l]*p0 + row[l+64]*p1 + row[l+128]*p2 + row[l+192]*p3;
    #pragma unroll
    for (int off = 32; off; off >>= 1) s += __shfl_xor(s, off);
    if (l == 0) xsh[j] = s;
  }
  __syncthreads();
  float x = xsh[t] + pb[t];
  float s = x;
  #pragma unroll
  for (int off = 32; off; off >>= 1) s += __shfl_xor(s, off);
  if (l == 0) rs[w] = s;
  __syncthreads();
  float mu = (rs[0]+rs[1]+rs[2]+rs[3]) * (1.0f/256.0f);
  float d = x - mu;
  float s2 = d*d;
  #pragma unroll
  for (int off = 32; off; off >>= 1) s2 += __shfl_xor(s2, off);
  if (l == 0) rs2[w] = s2;
  __syncthreads();
  float var = (rs2[0]+rs2[1]+rs2[2]+rs2[3]) * (1.0f/256.0f);
  float v = d / sqrtf(var + 1e-5f) * pg[t] + pbeta[t];
  scale[b*256 + t] = spikef(v);
  if (b == 0 && t == 0) {
    float mn = funkey(mm[0]), mx = funkey(mm[1]);
    gpar[0] = mn;
    gpar[1] = mx - mn + 1e-6f;
  }
}

// ---------------- Kernel 4: fusion map + normalized mi map ----------------
__global__ __launch_bounds__(256) void fuse_kernel(
    const float4* __restrict__ fm4, const float* __restrict__ scale,
    const float4* __restrict__ mi4, const float* __restrict__ gpar,
    float4* __restrict__ out4, float4* __restrict__ mi4out)
{
  const int c = blockIdx.x, b = blockIdx.y, t = threadIdx.x;
  if (c < 256) {
    float s = scale[b * 256 + c];
    size_t base = ((size_t)b * 256 + c) * 784;
    #pragma unroll
    for (int i = 0; i < 3; ++i) {
      int idx = t + i * 256;
      float4 v = fm4[base + idx];
      out4[base + idx] = make_float4(v.x*s, v.y*s, v.z*s, v.w*s);
    }
    int idx = t + 768;
    if (idx < 784) {
      float4 v = fm4[base + idx];
      out4[base + idx] = make_float4(v.x*s, v.y*s, v.z*s, v.w*s);
    }
  } else {
    float gmin = gpar[0], den = gpar[1];
    size_t base = (size_t)b * 784;
    #pragma unroll
    for (int i = 0; i < 3; ++i) {
      int idx = t + i * 256;
      float4 v = mi4[base + idx];
      mi4out[base + idx] = make_float4((v.x-gmin)/den, (v.y-gmin)/den,
                                       (v.z-gmin)/den, (v.w-gmin)/den);
    }
    int idx = t + 768;
    if (idx < 784) {
      float4 v = mi4[base + idx];
      mi4out[base + idx] = make_float4((v.x-gmin)/den, (v.y-gmin)/den,
                                       (v.z-gmin)/den, (v.w-gmin)/den);
    }
  }
}

extern "C" void kernel_launch(void* const* d_in, const int* in_sizes, int n_in,
                              void* d_out, int out_size, void* d_ws, size_t ws_size,
                              hipStream_t stream)
{
  const float* fm    = (const float*)d_in[0];
  const float* audio = (const float*)d_in[1];
  const float* w1    = (const float*)d_in[2];
  const float* b1    = (const float*)d_in[3];
  const float* g1    = (const float*)d_in[4];
  const float* be1   = (const float*)d_in[5];
  const float* w2    = (const float*)d_in[6];
  const float* b2    = (const float*)d_in[7];
  const float* g2    = (const float*)d_in[8];
  const float* be2   = (const float*)d_in[9];
  const float* w3    = (const float*)d_in[10];
  const float* b3    = (const float*)d_in[11];
  const float* pw    = (const float*)d_in[12];
  const float* pb    = (const float*)d_in[13];
  const float* pg    = (const float*)d_in[14];
  const float* pbeta = (const float*)d_in[15];

  float* ws    = (float*)d_ws;
  float* a_pre = ws;               // 2048 floats
  float* pool  = ws + 2048;        // 4096
  float* scale = ws + 6144;        // 4096
  float* mi    = ws + 10240;       // 50176 (16B aligned)
  float* w1t   = ws + 60416;       // 32768  [c][j]
  float* w2t   = ws + 93184;       // 8192   [k][j2]
  unsigned* mm = (unsigned*)(ws + 101376);  // 2 keys
  float* gpar  = ws + 101378;      // gmin, denom

  float* out    = (float*)d_out;
  float* mi4out = out + NPOS;

  prep_kernel<<<177, 256, 0, stream>>>(audio, w1, b1, w2, a_pre, w1t, w2t,
                                       pool, mm);
  mlp_kernel<<<dim3(49, 16), 256, 0, stream>>>(fm, w1t, w2t, b2, w3, b3,
                                               g1, be1, g2, be2,
                                               a_pre, mi, pool, mm);
  scale_kernel<<<16, 256, 0, stream>>>(pool, pw, pb, pg, pbeta, scale, mm, gpar);
  fuse_kernel<<<dim3(257, 16), 256, 0, stream>>>((const float4*)fm, scale,
                                                 (const float4*)mi, gpar,
                                                 (float4*)out, (float4*)mi4out);
}